// Round 3
// baseline (113.914 us; speedup 1.0000x reference)
//
#include <hip/hip_runtime.h>

#define D_OUT 1024
#define BATCH 65536
#define NBLOCKS 2048
#define UNROLL 4   // BATCH / (UNROLL*NBLOCKS) = 8 iterations exactly

typedef float f32x4 __attribute__((ext_vector_type(4)));

// fast tanh: 1 - 2/(e^{2v}+1). 5 ops, 2 transcendental, no clamp needed:
//   v->+inf: e=inf, rcp=0 -> 1 ;  v->-inf: e=0, rcp(1)=1 -> -1. No NaN path.
__device__ __forceinline__ float ftanh(float v) {
    float e = __expf(2.0f * v);
    return fmaf(-2.0f, __builtin_amdgcn_rcpf(e + 1.0f), 1.0f);
}

__device__ __forceinline__ f32x4 affine4(f32x4 h, f32x4 w, f32x4 b) {
    f32x4 r;
#pragma unroll
    for (int i = 0; i < 4; ++i) r[i] = fmaf(h[i], w[i], b[i]);
    return r;
}

__device__ __forceinline__ f32x4 tanh4(f32x4 h) {
    f32x4 r;
#pragma unroll
    for (int i = 0; i < 4; ++i) r[i] = ftanh(h[i]);
    return r;
}

__global__ __launch_bounds__(256, 4) void OneToOneDeepNet_kernel(
        const float* __restrict__ x,
        const float* __restrict__ W,
        const float* __restrict__ B,
        float* __restrict__ out) {
    const int t = threadIdx.x;      // 0..255
    const int col4 = t << 2;        // this thread's 4 columns

    // Per-channel params: 4 layers x (w,b) x f32x4 = 32 VGPRs, loaded once.
    const f32x4 w0 = *(const f32x4*)(W + 0 * D_OUT + col4);
    const f32x4 w1 = *(const f32x4*)(W + 1 * D_OUT + col4);
    const f32x4 w2 = *(const f32x4*)(W + 2 * D_OUT + col4);
    const f32x4 w3 = *(const f32x4*)(W + 3 * D_OUT + col4);
    const f32x4 b0 = *(const f32x4*)(B + 0 * D_OUT + col4);
    const f32x4 b1 = *(const f32x4*)(B + 1 * D_OUT + col4);
    const f32x4 b2 = *(const f32x4*)(B + 2 * D_OUT + col4);
    const f32x4 b3 = *(const f32x4*)(B + 3 * D_OUT + col4);

    // One block-iteration = UNROLL rows, all loads issued before any compute
    // (4 outstanding 16B loads/thread for latency hiding).
    for (int base = blockIdx.x; base < BATCH; base += UNROLL * NBLOCKS) {
        size_t off[UNROLL];
        f32x4 h[UNROLL];
#pragma unroll
        for (int k = 0; k < UNROLL; ++k) {
            off[k] = (size_t)(base + k * NBLOCKS) * D_OUT + col4;
            h[k] = __builtin_nontemporal_load((const f32x4*)(x + off[k]));
        }
#pragma unroll
        for (int k = 0; k < UNROLL; ++k) {
            f32x4 v = h[k];
            v = tanh4(affine4(v, w0, b0));
            v = tanh4(affine4(v, w1, b1));
            v = tanh4(affine4(v, w2, b2));
            v = affine4(v, w3, b3);
            __builtin_nontemporal_store(v, (f32x4*)(out + off[k]));
        }
    }
}

extern "C" void kernel_launch(void* const* d_in, const int* in_sizes, int n_in,
                              void* d_out, int out_size, void* d_ws, size_t ws_size,
                              hipStream_t stream) {
    const float* x = (const float*)d_in[0];
    const float* W = (const float*)d_in[1];
    const float* B = (const float*)d_in[2];
    float* out = (float*)d_out;
    OneToOneDeepNet_kernel<<<NBLOCKS, 256, 0, stream>>>(x, W, B, out);
}

// Round 4
// 112.954 us; speedup vs baseline: 1.0085x; 1.0085x over previous
//
#include <hip/hip_runtime.h>

#define D_OUT 1024
#define BATCH 65536
#define NBLOCKS 2048
#define UNROLL 2
#define STEP (UNROLL * NBLOCKS)   // 4096 rows per loop sweep

typedef float f32x4 __attribute__((ext_vector_type(4)));

// fast tanh: 1 - 2/(e^{2v}+1). 5 ops, 2 transcendental, no clamp needed:
//   v->+inf: e=inf, rcp=0 -> 1 ;  v->-inf: e=0, rcp(1)=1 -> -1. No NaN path.
__device__ __forceinline__ float ftanh(float v) {
    float e = __expf(2.0f * v);
    return fmaf(-2.0f, __builtin_amdgcn_rcpf(e + 1.0f), 1.0f);
}

__device__ __forceinline__ f32x4 affine4(f32x4 h, f32x4 w, f32x4 b) {
    f32x4 r;
#pragma unroll
    for (int i = 0; i < 4; ++i) r[i] = fmaf(h[i], w[i], b[i]);
    return r;
}

__device__ __forceinline__ f32x4 tanh4(f32x4 h) {
    f32x4 r;
#pragma unroll
    for (int i = 0; i < 4; ++i) r[i] = ftanh(h[i]);
    return r;
}

// 8 waves/EU (VGPR cap 64): 32 param regs + 2x f32x4 working set + u32
// addressing should fit; high TLP is what hides the ~300-cycle VALU chain
// between load and store.
__global__ __launch_bounds__(256, 8) void OneToOneDeepNet_kernel(
        const float* __restrict__ x,
        const float* __restrict__ W,
        const float* __restrict__ B,
        float* __restrict__ out) {
    const unsigned col = threadIdx.x << 2;   // this thread's first column

    // Per-channel params: 4 layers x (w,b) x f32x4 = 32 VGPRs, loaded once.
    const f32x4 w0 = *(const f32x4*)(W + 0 * D_OUT + col);
    const f32x4 w1 = *(const f32x4*)(W + 1 * D_OUT + col);
    const f32x4 w2 = *(const f32x4*)(W + 2 * D_OUT + col);
    const f32x4 w3 = *(const f32x4*)(W + 3 * D_OUT + col);
    const f32x4 b0 = *(const f32x4*)(B + 0 * D_OUT + col);
    const f32x4 b1 = *(const f32x4*)(B + 1 * D_OUT + col);
    const f32x4 b2 = *(const f32x4*)(B + 2 * D_OUT + col);
    const f32x4 b3 = *(const f32x4*)(B + 3 * D_OUT + col);

    // Two uniform streams NBLOCKS rows apart -> loads become
    // global_load_dwordx4 v, v_off(u32), s[base] (scalar base, no 64-bit
    // per-lane address math).
    const float* __restrict__ x0 = x;
    const float* __restrict__ x1 = x + (size_t)NBLOCKS * D_OUT;
    float* __restrict__ o0 = out;
    float* __restrict__ o1 = out + (size_t)NBLOCKS * D_OUT;

    for (unsigned base = blockIdx.x; base < BATCH; base += STEP) {
        const unsigned off = base * D_OUT + col;   // max ~65M elems, fits u32
        // Issue both loads before any dependent compute.
        f32x4 h0 = *(const f32x4*)(x0 + off);
        f32x4 h1 = *(const f32x4*)(x1 + off);
        // Interleave the two rows' chains for ILP in the trans pipe.
        h0 = tanh4(affine4(h0, w0, b0));
        h1 = tanh4(affine4(h1, w0, b0));
        h0 = tanh4(affine4(h0, w1, b1));
        h1 = tanh4(affine4(h1, w1, b1));
        h0 = tanh4(affine4(h0, w2, b2));
        h1 = tanh4(affine4(h1, w2, b2));
        h0 = affine4(h0, w3, b3);
        h1 = affine4(h1, w3, b3);
        *(f32x4*)(o0 + off) = h0;
        *(f32x4*)(o1 + off) = h1;
    }
}

extern "C" void kernel_launch(void* const* d_in, const int* in_sizes, int n_in,
                              void* d_out, int out_size, void* d_ws, size_t ws_size,
                              hipStream_t stream) {
    const float* x = (const float*)d_in[0];
    const float* W = (const float*)d_in[1];
    const float* B = (const float*)d_in[2];
    float* out = (float*)d_out;
    OneToOneDeepNet_kernel<<<NBLOCKS, 256, 0, stream>>>(x, W, B, out);
}